// Round 1
// baseline (1033.164 us; speedup 1.0000x reference)
//
#include <hip/hip_runtime.h>

#define NF 128      // feature dim (hidden = input = 128)
#define OUTF 64     // final output dim

// ---------------- degree / norm ----------------

__global__ void k_deg_init(float* __restrict__ deg, int n) {
    int i = blockIdx.x * blockDim.x + threadIdx.x;
    if (i < n) deg[i] = 1.0f;   // self-loop contributes 1
}

__global__ void k_deg_count(const int* __restrict__ dst, float* __restrict__ deg, int e) {
    int i = blockIdx.x * blockDim.x + threadIdx.x;
    if (i < e) atomicAdd(&deg[dst[i]], 1.0f);
}

__global__ void k_dinv(const float* __restrict__ deg, float* __restrict__ dinv, int n) {
    int i = blockIdx.x * blockDim.x + threadIdx.x;
    if (i < n) {
        float d = deg[i];
        dinv[i] = d > 0.0f ? rsqrtf(d) : 0.0f;
    }
}

// ---------------- GEMM: H = X @ W, fused self-loop agg init ----------------
// X: n x 128 row-major, W: 128 x 128 row-major.
// Block: 256 threads, tile 64 rows x 64 cols, 4x4 per thread.
// K=128 staged entirely in LDS (x-tile transposed for ds_read_b128).

__global__ __launch_bounds__(256) void k_gemm_agginit(
    const float* __restrict__ X, const float* __restrict__ W,
    const float* __restrict__ dinv,
    float* __restrict__ H, float* __restrict__ AGG, int n)
{
    __shared__ float xs[128][68];   // [k][r], pad 64->68 keeps 16B align, breaks pow2 stride
    __shared__ float ws[128][64];   // [k][c_local]

    const int t    = threadIdx.x;
    const int bRow = blockIdx.x * 64;
    const int c0   = blockIdx.y * 64;

    // stage X tile (64 rows x 128 k), transposed into xs[k][r]
    #pragma unroll
    for (int i = 0; i < 8; ++i) {
        int idx = i * 256 + t;          // 0..2047 over 64 r x 32 k4
        int r   = idx >> 5;
        int k4  = idx & 31;
        int gr  = bRow + r;
        float4 v = make_float4(0.f, 0.f, 0.f, 0.f);
        if (gr < n) v = *(const float4*)&X[(size_t)gr * NF + k4 * 4];
        xs[k4 * 4 + 0][r] = v.x;
        xs[k4 * 4 + 1][r] = v.y;
        xs[k4 * 4 + 2][r] = v.z;
        xs[k4 * 4 + 3][r] = v.w;
    }
    // stage W tile (128 k x 64 cols)
    #pragma unroll
    for (int i = 0; i < 8; ++i) {
        int idx = i * 256 + t;          // over 128 k x 16 c4
        int k   = idx >> 4;
        int c4  = idx & 15;
        *(float4*)&ws[k][c4 * 4] = *(const float4*)&W[(size_t)k * NF + c0 + c4 * 4];
    }
    __syncthreads();

    const int tx = t & 15;   // col group
    const int ty = t >> 4;   // row group
    float acc[4][4] = {};

    #pragma unroll 16
    for (int k = 0; k < 128; ++k) {
        float4 a = *(float4*)&xs[k][ty * 4];
        float4 b = *(float4*)&ws[k][tx * 4];
        acc[0][0] += a.x * b.x; acc[0][1] += a.x * b.y; acc[0][2] += a.x * b.z; acc[0][3] += a.x * b.w;
        acc[1][0] += a.y * b.x; acc[1][1] += a.y * b.y; acc[1][2] += a.y * b.z; acc[1][3] += a.y * b.w;
        acc[2][0] += a.z * b.x; acc[2][1] += a.z * b.y; acc[2][2] += a.z * b.z; acc[2][3] += a.z * b.w;
        acc[3][0] += a.w * b.x; acc[3][1] += a.w * b.y; acc[3][2] += a.w * b.z; acc[3][3] += a.w * b.w;
    }

    #pragma unroll
    for (int i = 0; i < 4; ++i) {
        int gr = bRow + ty * 4 + i;
        if (gr >= n) continue;
        float di = dinv[gr];
        float s  = di * di;
        float4 hv = make_float4(acc[i][0], acc[i][1], acc[i][2], acc[i][3]);
        size_t off = (size_t)gr * NF + c0 + tx * 4;
        *(float4*)&H[off] = hv;
        float4 av = make_float4(hv.x * s, hv.y * s, hv.z * s, hv.w * s);
        *(float4*)&AGG[off] = av;
    }
}

// ---------------- edge scatter: AGG[dst] += H[src] * dinv[src]*dinv[dst] ----------------
// 2 edges per 256-thread block; each wave (64 lanes) has a uniform edge.

__global__ __launch_bounds__(256) void k_scatter(
    const int* __restrict__ src, const int* __restrict__ dst,
    const float* __restrict__ dinv, const float* __restrict__ H,
    float* __restrict__ AGG, int e)
{
    int e0 = blockIdx.x * 2 + (threadIdx.x >> 7);
    int f  = threadIdx.x & 127;
    if (e0 >= e) return;
    int s = src[e0];
    int d = dst[e0];
    float w = dinv[s] * dinv[d];
    atomicAdd(&AGG[(size_t)d * NF + f], H[(size_t)s * NF + f] * w);
}

// ---------------- bias + relu (in place agg -> x_next) ----------------

__global__ void k_bias_relu(float* __restrict__ AGG, const float* __restrict__ b, int n4) {
    int i = blockIdx.x * blockDim.x + threadIdx.x;  // over n*NF/4 float4s
    if (i >= n4) return;
    int f4 = i & (NF / 4 - 1);
    float4 v  = ((const float4*)AGG)[i];
    float4 bb = ((const float4*)b)[f4];
    v.x = fmaxf(v.x + bb.x, 0.f);
    v.y = fmaxf(v.y + bb.y, 0.f);
    v.z = fmaxf(v.z + bb.z, 0.f);
    v.w = fmaxf(v.w + bb.w, 0.f);
    ((float4*)AGG)[i] = v;
}

// ---------------- final fc on last node's embedding ----------------

__global__ void k_fc(const float* __restrict__ X3, const float* __restrict__ fcW,
                     const float* __restrict__ fcb, float* __restrict__ out, int n)
{
    __shared__ float xrow[NF];
    int j = threadIdx.x;            // 0..63
    xrow[j]      = X3[(size_t)(n - 1) * NF + j];
    xrow[j + 64] = X3[(size_t)(n - 1) * NF + j + 64];
    __syncthreads();
    float acc = fcb[j];
    #pragma unroll 16
    for (int k = 0; k < NF; ++k) acc += xrow[k] * fcW[k * OUTF + j];
    out[j] = acc;
}

// ---------------- launch ----------------

extern "C" void kernel_launch(void* const* d_in, const int* in_sizes, int n_in,
                              void* d_out, int out_size, void* d_ws, size_t ws_size,
                              hipStream_t stream)
{
    const float* x    = (const float*)d_in[0];
    const int*   ei   = (const int*)d_in[1];
    const float* W1   = (const float*)d_in[2];
    const float* b1   = (const float*)d_in[3];
    const float* W2   = (const float*)d_in[4];
    const float* b2   = (const float*)d_in[5];
    const float* W3   = (const float*)d_in[6];
    const float* b3   = (const float*)d_in[7];
    const float* fcW  = (const float*)d_in[8];
    const float* fcb  = (const float*)d_in[9];
    float* out = (float*)d_out;

    const int n = in_sizes[0] / NF;       // 50000
    const int E = in_sizes[1] / 2;        // 600000
    const int* src = ei;
    const int* dst = ei + E;

    float* ws   = (float*)d_ws;
    float* deg  = ws;                     // n floats
    float* dinv = ws + 65536;             // n floats
    float* H    = ws + 2 * 65536;         // n*NF
    float* bufA = H    + (size_t)n * NF;  // n*NF
    float* bufB = bufA + (size_t)n * NF;  // n*NF

    const int B = 256;

    // prep: degrees + norm
    k_deg_init<<<(n + B - 1) / B, B, 0, stream>>>(deg, n);
    k_deg_count<<<(E + B - 1) / B, B, 0, stream>>>(dst, deg, E);
    k_dinv<<<(n + B - 1) / B, B, 0, stream>>>(deg, dinv, n);

    dim3 gGemm((n + 63) / 64, NF / 64);
    int  gScat = (E + 1) / 2;
    int  n4    = n * NF / 4;
    int  gRelu = (n4 + B - 1) / B;

    // layer 1: x -> bufA
    k_gemm_agginit<<<gGemm, B, 0, stream>>>(x, W1, dinv, H, bufA, n);
    k_scatter<<<gScat, B, 0, stream>>>(src, dst, dinv, H, bufA, E);
    k_bias_relu<<<gRelu, B, 0, stream>>>(bufA, b1, n4);

    // layer 2: bufA -> bufB
    k_gemm_agginit<<<gGemm, B, 0, stream>>>(bufA, W2, dinv, H, bufB, n);
    k_scatter<<<gScat, B, 0, stream>>>(src, dst, dinv, H, bufB, E);
    k_bias_relu<<<gRelu, B, 0, stream>>>(bufB, b2, n4);

    // layer 3: bufB -> bufA
    k_gemm_agginit<<<gGemm, B, 0, stream>>>(bufB, W3, dinv, H, bufA, n);
    k_scatter<<<gScat, B, 0, stream>>>(src, dst, dinv, H, bufA, E);
    k_bias_relu<<<gRelu, B, 0, stream>>>(bufA, b3, n4);

    // final fc on node n-1
    k_fc<<<1, 64, 0, stream>>>(bufA, fcW, fcb, out, n);
}

// Round 2
// 424.920 us; speedup vs baseline: 2.4314x; 2.4314x over previous
//
#include <hip/hip_runtime.h>

#define NF 128      // feature dim
#define OUTF 64     // final output dim
#define SCAN_B 256
#define SCAN_ITEMS 8            // 2048 elements per scan block

// ---------------- degree histogram / norm ----------------

__global__ void k_count(const int* __restrict__ dst, int* __restrict__ cnt, int e) {
    int i = blockIdx.x * blockDim.x + threadIdx.x;
    if (i < e) atomicAdd(&cnt[dst[i]], 1);
}

// dinv[i] = rsqrt(1 + in_degree)   (the +1 is the self loop)
__global__ void k_dinv(const int* __restrict__ cnt, float* __restrict__ dinv,
                       int* __restrict__ offsets, int n, int e) {
    int i = blockIdx.x * blockDim.x + threadIdx.x;
    if (i < n) dinv[i] = rsqrtf(1.0f + (float)cnt[i]);
    if (i == 0) offsets[n] = e;   // sentinel; scan kernels fill offsets[0..n-1]
}

// ---------------- hierarchical exclusive scan of cnt -> offsets ----------------

__global__ void k_scan1(const int* __restrict__ cnt, int* __restrict__ part, int n) {
    __shared__ int lds[SCAN_B];
    int t = threadIdx.x;
    int base = blockIdx.x * SCAN_B * SCAN_ITEMS;
    int s = 0;
    #pragma unroll
    for (int j = 0; j < SCAN_ITEMS; ++j) {
        int idx = base + j * SCAN_B + t;
        if (idx < n) s += cnt[idx];
    }
    lds[t] = s; __syncthreads();
    for (int off = SCAN_B / 2; off > 0; off >>= 1) {
        if (t < off) lds[t] += lds[t + off];
        __syncthreads();
    }
    if (t == 0) part[blockIdx.x] = lds[0];
}

__global__ void k_scan2(int* __restrict__ part, int nb) {
    if (threadIdx.x == 0) {
        int run = 0;
        for (int i = 0; i < nb; ++i) { int v = part[i]; part[i] = run; run += v; }
    }
}

__global__ void k_scan3(const int* __restrict__ cnt, const int* __restrict__ part,
                        int* __restrict__ offsets, int n) {
    __shared__ int lds[SCAN_B];
    int t = threadIdx.x;
    int base = blockIdx.x * SCAN_B * SCAN_ITEMS + t * SCAN_ITEMS;
    int v[SCAN_ITEMS];
    int s = 0;
    #pragma unroll
    for (int j = 0; j < SCAN_ITEMS; ++j) {
        int idx = base + j;
        v[j] = (idx < n) ? cnt[idx] : 0;
        s += v[j];
    }
    lds[t] = s; __syncthreads();
    // Hillis-Steele inclusive scan
    for (int off = 1; off < SCAN_B; off <<= 1) {
        int tmp = (t >= off) ? lds[t - off] : 0;
        __syncthreads();
        lds[t] += tmp;
        __syncthreads();
    }
    int run = lds[t] - s + part[blockIdx.x];   // exclusive prefix for this thread
    #pragma unroll
    for (int j = 0; j < SCAN_ITEMS; ++j) {
        int idx = base + j;
        if (idx < n) offsets[idx] = run;
        run += v[j];
    }
}

// ---------------- bucket fill: CSR by dst, payload = (src, weight) ----------------

__global__ void k_bucket(const int* __restrict__ src, const int* __restrict__ dst,
                         const float* __restrict__ dinv, const int* __restrict__ offsets,
                         int* __restrict__ cursor, int2* __restrict__ eData, int e) {
    int i = blockIdx.x * blockDim.x + threadIdx.x;
    if (i >= e) return;
    int s = src[i], d = dst[i];
    int p = offsets[d] + atomicAdd(&cursor[d], 1);
    eData[p] = make_int2(s, __float_as_int(dinv[s] * dinv[d]));
}

// ---------------- GEMM: H = X @ W ----------------
// 64x64 tile / block of 256, 4x4 register tile, K=128 fully in LDS.

__global__ __launch_bounds__(256) void k_gemm(
    const float* __restrict__ X, const float* __restrict__ W,
    float* __restrict__ H, int n)
{
    __shared__ float xs[128][68];   // [k][r], padded
    __shared__ float ws[128][64];   // [k][c_local]

    const int t    = threadIdx.x;
    const int bRow = blockIdx.x * 64;
    const int c0   = blockIdx.y * 64;

    #pragma unroll
    for (int i = 0; i < 8; ++i) {
        int idx = i * 256 + t;
        int r   = idx >> 5;
        int k4  = idx & 31;
        int gr  = bRow + r;
        float4 v = make_float4(0.f, 0.f, 0.f, 0.f);
        if (gr < n) v = *(const float4*)&X[(size_t)gr * NF + k4 * 4];
        xs[k4 * 4 + 0][r] = v.x;
        xs[k4 * 4 + 1][r] = v.y;
        xs[k4 * 4 + 2][r] = v.z;
        xs[k4 * 4 + 3][r] = v.w;
    }
    #pragma unroll
    for (int i = 0; i < 8; ++i) {
        int idx = i * 256 + t;
        int k   = idx >> 4;
        int c4  = idx & 15;
        *(float4*)&ws[k][c4 * 4] = *(const float4*)&W[(size_t)k * NF + c0 + c4 * 4];
    }
    __syncthreads();

    const int tx = t & 15;
    const int ty = t >> 4;
    float acc[4][4] = {};

    #pragma unroll 16
    for (int k = 0; k < 128; ++k) {
        float4 a = *(float4*)&xs[k][ty * 4];
        float4 b = *(float4*)&ws[k][tx * 4];
        acc[0][0] += a.x * b.x; acc[0][1] += a.x * b.y; acc[0][2] += a.x * b.z; acc[0][3] += a.x * b.w;
        acc[1][0] += a.y * b.x; acc[1][1] += a.y * b.y; acc[1][2] += a.y * b.z; acc[1][3] += a.y * b.w;
        acc[2][0] += a.z * b.x; acc[2][1] += a.z * b.y; acc[2][2] += a.z * b.z; acc[2][3] += a.z * b.w;
        acc[3][0] += a.w * b.x; acc[3][1] += a.w * b.y; acc[3][2] += a.w * b.z; acc[3][3] += a.w * b.w;
    }

    #pragma unroll
    for (int i = 0; i < 4; ++i) {
        int gr = bRow + ty * 4 + i;
        if (gr >= n) continue;
        *(float4*)&H[(size_t)gr * NF + c0 + tx * 4] =
            make_float4(acc[i][0], acc[i][1], acc[i][2], acc[i][3]);
    }
}

// ---------------- pull gather: Xout[d] = relu(b + dinv[d]^2*H[d] + sum_in H[s]*w) ----------------
// One wave (64 lanes) per destination node, float2 per lane.

__global__ __launch_bounds__(256) void k_gather(
    const int* __restrict__ offsets, const int2* __restrict__ eData,
    const float* __restrict__ dinv, const float* __restrict__ H,
    const float* __restrict__ bias, float* __restrict__ Xout, int n)
{
    int d = (blockIdx.x * 256 + threadIdx.x) >> 6;
    int lane = threadIdx.x & 63;
    if (d >= n) return;

    const float2* H2 = (const float2*)H;
    int beg = offsets[d];
    int end = offsets[d + 1];

    float di = dinv[d];
    float s2 = di * di;
    float2 h = H2[(size_t)d * 64 + lane];
    float accx = h.x * s2, accy = h.y * s2;

    int p = beg;
    for (; p + 1 < end; p += 2) {           // unroll-2: two row loads in flight
        int2 e0 = eData[p];
        int2 e1 = eData[p + 1];
        float w0 = __int_as_float(e0.y);
        float w1 = __int_as_float(e1.y);
        float2 h0 = H2[(size_t)e0.x * 64 + lane];
        float2 h1 = H2[(size_t)e1.x * 64 + lane];
        accx += h0.x * w0 + h1.x * w1;
        accy += h0.y * w0 + h1.y * w1;
    }
    if (p < end) {
        int2 e0 = eData[p];
        float w0 = __int_as_float(e0.y);
        float2 h0 = H2[(size_t)e0.x * 64 + lane];
        accx += h0.x * w0;
        accy += h0.y * w0;
    }

    float2 bb = ((const float2*)bias)[lane];
    float2 out;
    out.x = fmaxf(accx + bb.x, 0.f);
    out.y = fmaxf(accy + bb.y, 0.f);
    ((float2*)Xout)[(size_t)d * 64 + lane] = out;
}

// ---------------- final fc on last node's embedding ----------------

__global__ void k_fc(const float* __restrict__ X3, const float* __restrict__ fcW,
                     const float* __restrict__ fcb, float* __restrict__ out, int n)
{
    __shared__ float xrow[NF];
    int j = threadIdx.x;            // 0..63
    xrow[j]      = X3[(size_t)(n - 1) * NF + j];
    xrow[j + 64] = X3[(size_t)(n - 1) * NF + j + 64];
    __syncthreads();
    float acc = fcb[j];
    #pragma unroll 16
    for (int k = 0; k < NF; ++k) acc += xrow[k] * fcW[k * OUTF + j];
    out[j] = acc;
}

// ---------------- launch ----------------

extern "C" void kernel_launch(void* const* d_in, const int* in_sizes, int n_in,
                              void* d_out, int out_size, void* d_ws, size_t ws_size,
                              hipStream_t stream)
{
    const float* x    = (const float*)d_in[0];
    const int*   ei   = (const int*)d_in[1];
    const float* W1   = (const float*)d_in[2];
    const float* b1   = (const float*)d_in[3];
    const float* W2   = (const float*)d_in[4];
    const float* b2   = (const float*)d_in[5];
    const float* W3   = (const float*)d_in[6];
    const float* b3   = (const float*)d_in[7];
    const float* fcW  = (const float*)d_in[8];
    const float* fcb  = (const float*)d_in[9];
    float* out = (float*)d_out;

    const int n = in_sizes[0] / NF;       // 50000
    const int E = in_sizes[1] / 2;        // 600000
    const int* src = ei;
    const int* dst = ei + E;

    // workspace carve-up (256B aligned)
    char* wp = (char*)d_ws;
    auto alloc = [&](size_t bytes) -> void* {
        void* r = (void*)wp;
        wp += (bytes + 255) & ~(size_t)255;
        return r;
    };
    int*   cnt     = (int*)  alloc((size_t)n * 4);
    float* dinv    = (float*)alloc((size_t)n * 4);
    int*   offsets = (int*)  alloc((size_t)(n + 1) * 4);
    int*   cursor  = (int*)  alloc((size_t)n * 4);
    int*   part    = (int*)  alloc(128 * 4);
    int2*  eData   = (int2*) alloc((size_t)E * 8);
    float* H       = (float*)alloc((size_t)n * NF * 4);
    float* bufA    = (float*)alloc((size_t)n * NF * 4);
    float* bufB    = (float*)alloc((size_t)n * NF * 4);

    const int B = 256;
    const int nb = (n + SCAN_B * SCAN_ITEMS - 1) / (SCAN_B * SCAN_ITEMS);  // 25

    hipMemsetAsync(cnt,    0, (size_t)n * 4, stream);
    hipMemsetAsync(cursor, 0, (size_t)n * 4, stream);

    k_count<<<(E + B - 1) / B, B, 0, stream>>>(dst, cnt, E);
    k_dinv <<<(n + B - 1) / B, B, 0, stream>>>(cnt, dinv, offsets, n, E);
    k_scan1<<<nb, SCAN_B, 0, stream>>>(cnt, part, n);
    k_scan2<<<1, 64, 0, stream>>>(part, nb);
    k_scan3<<<nb, SCAN_B, 0, stream>>>(cnt, part, offsets, n);
    k_bucket<<<(E + B - 1) / B, B, 0, stream>>>(src, dst, dinv, offsets, cursor, eData, E);

    dim3 gGemm((n + 63) / 64, NF / 64);
    int  gGath = (n * 64 + 255) / 256;     // one wave per node

    // layer 1: x -> bufA
    k_gemm  <<<gGemm, B, 0, stream>>>(x, W1, H, n);
    k_gather<<<gGath, B, 0, stream>>>(offsets, eData, dinv, H, b1, bufA, n);
    // layer 2: bufA -> bufB
    k_gemm  <<<gGemm, B, 0, stream>>>(bufA, W2, H, n);
    k_gather<<<gGath, B, 0, stream>>>(offsets, eData, dinv, H, b2, bufB, n);
    // layer 3: bufB -> bufA
    k_gemm  <<<gGemm, B, 0, stream>>>(bufB, W3, H, n);
    k_gather<<<gGath, B, 0, stream>>>(offsets, eData, dinv, H, b3, bufA, n);

    // final fc on node n-1
    k_fc<<<1, 64, 0, stream>>>(bufA, fcW, fcb, out, n);
}

// Round 3
// 336.971 us; speedup vs baseline: 3.0660x; 1.2610x over previous
//
#include <hip/hip_runtime.h>

#define NF 128      // feature dim
#define OUTF 64     // final output dim
#define SCAN_B 256
#define SCAN_ITEMS 8            // 2048 elements per scan block

typedef _Float16 f16;
typedef _Float16 f16x2 __attribute__((ext_vector_type(2)));
typedef _Float16 f16x4 __attribute__((ext_vector_type(4)));
typedef _Float16 f16x8 __attribute__((ext_vector_type(8)));
typedef float    f32x4 __attribute__((ext_vector_type(4)));

// ---------------- degree histogram / norm ----------------

__global__ void k_count(const int* __restrict__ dst, int* __restrict__ cnt, int e) {
    int i = blockIdx.x * blockDim.x + threadIdx.x;
    if (i < e) atomicAdd(&cnt[dst[i]], 1);
}

// dinv[i] = rsqrt(1 + in_degree)
__global__ void k_dinv(const int* __restrict__ cnt, float* __restrict__ dinv,
                       int* __restrict__ offsets, int n, int e) {
    int i = blockIdx.x * blockDim.x + threadIdx.x;
    if (i < n) dinv[i] = rsqrtf(1.0f + (float)cnt[i]);
    if (i == 0) offsets[n] = e;
}

// ---------------- hierarchical exclusive scan ----------------

__global__ void k_scan1(const int* __restrict__ cnt, int* __restrict__ part, int n) {
    __shared__ int lds[SCAN_B];
    int t = threadIdx.x;
    int base = blockIdx.x * SCAN_B * SCAN_ITEMS;
    int s = 0;
    #pragma unroll
    for (int j = 0; j < SCAN_ITEMS; ++j) {
        int idx = base + j * SCAN_B + t;
        if (idx < n) s += cnt[idx];
    }
    lds[t] = s; __syncthreads();
    for (int off = SCAN_B / 2; off > 0; off >>= 1) {
        if (t < off) lds[t] += lds[t + off];
        __syncthreads();
    }
    if (t == 0) part[blockIdx.x] = lds[0];
}

__global__ void k_scan2(int* __restrict__ part, int nb) {
    if (threadIdx.x == 0) {
        int run = 0;
        for (int i = 0; i < nb; ++i) { int v = part[i]; part[i] = run; run += v; }
    }
}

__global__ void k_scan3(const int* __restrict__ cnt, const int* __restrict__ part,
                        int* __restrict__ offsets, int n) {
    __shared__ int lds[SCAN_B];
    int t = threadIdx.x;
    int base = blockIdx.x * SCAN_B * SCAN_ITEMS + t * SCAN_ITEMS;
    int v[SCAN_ITEMS];
    int s = 0;
    #pragma unroll
    for (int j = 0; j < SCAN_ITEMS; ++j) {
        int idx = base + j;
        v[j] = (idx < n) ? cnt[idx] : 0;
        s += v[j];
    }
    lds[t] = s; __syncthreads();
    for (int off = 1; off < SCAN_B; off <<= 1) {
        int tmp = (t >= off) ? lds[t - off] : 0;
        __syncthreads();
        lds[t] += tmp;
        __syncthreads();
    }
    int run = lds[t] - s + part[blockIdx.x];
    #pragma unroll
    for (int j = 0; j < SCAN_ITEMS; ++j) {
        int idx = base + j;
        if (idx < n) offsets[idx] = run;
        run += v[j];
    }
}

// ---------------- bucket fill: CSR by dst, payload (src, weight) ----------------

__global__ void k_bucket(const int* __restrict__ src, const int* __restrict__ dst,
                         const float* __restrict__ dinv, const int* __restrict__ offsets,
                         int* __restrict__ cursor, int2* __restrict__ eData, int e) {
    int i = blockIdx.x * blockDim.x + threadIdx.x;
    if (i >= e) return;
    int s = src[i], d = dst[i];
    int p = offsets[d] + atomicAdd(&cursor[d], 1);
    eData[p] = make_int2(s, __float_as_int(dinv[s] * dinv[d]));
}

// ---------------- conversions ----------------

// x fp32 -> fp16, 4 elems / thread
__global__ void k_tohalf(const float* __restrict__ in, f16* __restrict__ outh, int n4) {
    int i = blockIdx.x * blockDim.x + threadIdx.x;
    if (i >= n4) return;
    float4 v = ((const float4*)in)[i];
    f16x4 h = { (f16)v.x, (f16)v.y, (f16)v.z, (f16)v.w };
    ((f16x4*)outh)[i] = h;
}

// W (128x128 fp32, [k][n]) -> Wt (128x128 fp16, [n][k]); grid.y selects matrix
__global__ void k_wprep(const float* __restrict__ W0, const float* __restrict__ W1,
                        const float* __restrict__ W2, f16* __restrict__ Wt) {
    const float* W = (blockIdx.y == 0) ? W0 : (blockIdx.y == 1) ? W1 : W2;
    f16* T = Wt + (size_t)blockIdx.y * NF * NF;
    int idx = blockIdx.x * blockDim.x + threadIdx.x;   // 0..16383
    int j = idx >> 7;        // out row (n)
    int k = idx & 127;       // out col (k)
    T[idx] = (f16)W[k * NF + j];
}

// ---------------- GEMM: H = X @ W via MFMA f16, fp32 accumulate ----------------
// One wave per 16-row strip, full K=128 & N=128 in registers. B from
// transposed fp16 weights (L2-resident, 32 KB). No LDS.

__global__ __launch_bounds__(256) void k_gemm_h(
    const f16* __restrict__ X, const f16* __restrict__ Wt,
    f16* __restrict__ H, int n)
{
    const int wave = threadIdx.x >> 6;
    const int lane = threadIdx.x & 63;
    const int strip = blockIdx.x * 4 + wave;
    const int row0 = strip * 16;
    if (row0 >= n) return;

    const int m    = lane & 15;
    const int quad = lane >> 4;

    // A fragments for all 4 K-steps: A[row0+m][ks*32 + quad*8 + j]
    f16x8 a[4];
    const f16* arow = X + (size_t)(row0 + m) * NF + quad * 8;
    #pragma unroll
    for (int ks = 0; ks < 4; ++ks)
        a[ks] = *(const f16x8*)(arow + ks * 32);

    f32x4 acc[8];
    #pragma unroll
    for (int n0 = 0; n0 < 8; ++n0) acc[n0] = (f32x4){0.f, 0.f, 0.f, 0.f};

    #pragma unroll
    for (int n0 = 0; n0 < 8; ++n0) {
        const f16* brow = Wt + (size_t)(n0 * 16 + m) * NF + quad * 8;
        #pragma unroll
        for (int ks = 0; ks < 4; ++ks) {
            f16x8 b = *(const f16x8*)(brow + ks * 32);
            acc[n0] = __builtin_amdgcn_mfma_f32_16x16x32_f16(a[ks], b, acc[n0], 0, 0, 0);
        }
    }

    // C layout: col = lane&15, row = quad*4 + reg
    #pragma unroll
    for (int n0 = 0; n0 < 8; ++n0) {
        #pragma unroll
        for (int i = 0; i < 4; ++i) {
            int r = row0 + quad * 4 + i;
            H[(size_t)r * NF + n0 * 16 + m] = (f16)acc[n0][i];
        }
    }
}

// ---------------- pull gather: Xout[d] = relu(b + dinv^2*H[d] + sum H[s]*w) ----------------
// One wave per node, f16x2 per lane (256 B rows), fp32 accumulate, fp16 out.

__global__ __launch_bounds__(256) void k_gather(
    const int* __restrict__ offsets, const int2* __restrict__ eData,
    const float* __restrict__ dinv, const f16* __restrict__ H,
    const float* __restrict__ bias, f16* __restrict__ Xout, int n)
{
    int d = (blockIdx.x * 256 + threadIdx.x) >> 6;
    int lane = threadIdx.x & 63;
    if (d >= n) return;

    const f16x2* H2 = (const f16x2*)H;
    int beg = offsets[d];
    int end = offsets[d + 1];

    float di = dinv[d];
    float s2 = di * di;
    f16x2 h = H2[(size_t)d * 64 + lane];
    float accx = (float)h.x * s2, accy = (float)h.y * s2;

    int p = beg;
    for (; p + 3 < end; p += 4) {
        int2 e0 = eData[p];
        int2 e1 = eData[p + 1];
        int2 e2 = eData[p + 2];
        int2 e3 = eData[p + 3];
        f16x2 h0 = H2[(size_t)e0.x * 64 + lane];
        f16x2 h1 = H2[(size_t)e1.x * 64 + lane];
        f16x2 h2 = H2[(size_t)e2.x * 64 + lane];
        f16x2 h3 = H2[(size_t)e3.x * 64 + lane];
        float w0 = __int_as_float(e0.y), w1 = __int_as_float(e1.y);
        float w2 = __int_as_float(e2.y), w3 = __int_as_float(e3.y);
        accx += (float)h0.x * w0 + (float)h1.x * w1 + (float)h2.x * w2 + (float)h3.x * w3;
        accy += (float)h0.y * w0 + (float)h1.y * w1 + (float)h2.y * w2 + (float)h3.y * w3;
    }
    for (; p < end; ++p) {
        int2 e0 = eData[p];
        f16x2 h0 = H2[(size_t)e0.x * 64 + lane];
        float w0 = __int_as_float(e0.y);
        accx += (float)h0.x * w0;
        accy += (float)h0.y * w0;
    }

    float2 bb = ((const float2*)bias)[lane];
    f16x2 o;
    o.x = (f16)fmaxf(accx + bb.x, 0.f);
    o.y = (f16)fmaxf(accy + bb.y, 0.f);
    ((f16x2*)Xout)[(size_t)d * 64 + lane] = o;
}

// ---------------- final fc on last node's embedding ----------------

__global__ void k_fc(const f16* __restrict__ X3, const float* __restrict__ fcW,
                     const float* __restrict__ fcb, float* __restrict__ out, int n)
{
    __shared__ float xrow[NF];
    int j = threadIdx.x;            // 0..63
    xrow[j]      = (float)X3[(size_t)(n - 1) * NF + j];
    xrow[j + 64] = (float)X3[(size_t)(n - 1) * NF + j + 64];
    __syncthreads();
    float acc = fcb[j];
    #pragma unroll 16
    for (int k = 0; k < NF; ++k) acc += xrow[k] * fcW[k * OUTF + j];
    out[j] = acc;
}

// ---------------- launch ----------------

extern "C" void kernel_launch(void* const* d_in, const int* in_sizes, int n_in,
                              void* d_out, int out_size, void* d_ws, size_t ws_size,
                              hipStream_t stream)
{
    const float* x    = (const float*)d_in[0];
    const int*   ei   = (const int*)d_in[1];
    const float* W1   = (const float*)d_in[2];
    const float* b1   = (const float*)d_in[3];
    const float* W2   = (const float*)d_in[4];
    const float* b2   = (const float*)d_in[5];
    const float* W3   = (const float*)d_in[6];
    const float* b3   = (const float*)d_in[7];
    const float* fcW  = (const float*)d_in[8];
    const float* fcb  = (const float*)d_in[9];
    float* out = (float*)d_out;

    const int n = in_sizes[0] / NF;       // 50000
    const int E = in_sizes[1] / 2;        // 600000
    const int* src = ei;
    const int* dst = ei + E;

    char* wp = (char*)d_ws;
    auto alloc = [&](size_t bytes) -> void* {
        void* r = (void*)wp;
        wp += (bytes + 255) & ~(size_t)255;
        return r;
    };
    int*   cnt     = (int*)  alloc((size_t)n * 4);
    float* dinv    = (float*)alloc((size_t)n * 4);
    int*   offsets = (int*)  alloc((size_t)(n + 1) * 4);
    int*   cursor  = (int*)  alloc((size_t)n * 4);
    int*   part    = (int*)  alloc(128 * 4);
    int2*  eData   = (int2*) alloc((size_t)E * 8);
    f16*   Wt      = (f16*)  alloc((size_t)3 * NF * NF * 2);
    f16*   xh      = (f16*)  alloc((size_t)n * NF * 2);
    f16*   H       = (f16*)  alloc((size_t)n * NF * 2);
    f16*   bufA    = (f16*)  alloc((size_t)n * NF * 2);
    f16*   bufB    = (f16*)  alloc((size_t)n * NF * 2);

    const int B = 256;
    const int nb = (n + SCAN_B * SCAN_ITEMS - 1) / (SCAN_B * SCAN_ITEMS);  // 25

    hipMemsetAsync(cnt,    0, (size_t)n * 4, stream);
    hipMemsetAsync(cursor, 0, (size_t)n * 4, stream);

    // prep
    k_count<<<(E + B - 1) / B, B, 0, stream>>>(dst, cnt, E);
    k_dinv <<<(n + B - 1) / B, B, 0, stream>>>(cnt, dinv, offsets, n, E);
    k_scan1<<<nb, SCAN_B, 0, stream>>>(cnt, part, n);
    k_scan2<<<1, 64, 0, stream>>>(part, nb);
    k_scan3<<<nb, SCAN_B, 0, stream>>>(cnt, part, offsets, n);
    k_bucket<<<(E + B - 1) / B, B, 0, stream>>>(src, dst, dinv, offsets, cursor, eData, E);

    // fp16 conversions
    int n4 = n * NF / 4;
    k_tohalf<<<(n4 + B - 1) / B, B, 0, stream>>>(x, xh, n4);
    dim3 gW(64, 3);
    k_wprep<<<gW, B, 0, stream>>>(W1, W2, W3, Wt);

    dim3 gGemm((n + 63) / 64);
    int  gGath = (n * 64 + 255) / 256;

    // layer 1: xh -> bufA
    k_gemm_h<<<gGemm, B, 0, stream>>>(xh, Wt, H, n);
    k_gather<<<gGath, B, 0, stream>>>(offsets, eData, dinv, H, b1, bufA, n);
    // layer 2: bufA -> bufB
    k_gemm_h<<<gGemm, B, 0, stream>>>(bufA, Wt + NF * NF, H, n);
    k_gather<<<gGath, B, 0, stream>>>(offsets, eData, dinv, H, b2, bufB, n);
    // layer 3: bufB -> bufA
    k_gemm_h<<<gGemm, B, 0, stream>>>(bufB, Wt + 2 * NF * NF, H, n);
    k_gather<<<gGath, B, 0, stream>>>(offsets, eData, dinv, H, b3, bufA, n);

    // final fc on node n-1
    k_fc<<<1, 64, 0, stream>>>(bufA, fcW, fcb, out, n);
}

// Round 4
// 167.809 us; speedup vs baseline: 6.1568x; 2.0081x over previous
//
#include <hip/hip_runtime.h>

#define NF 128
#define OUTF 64

// mark bits
#define M2 1   // x2 needed (layer-2 gather frontier)
#define M1 2   // x1 needed (layer-1 gather frontier)
#define M0 4   // x0 needed (rows for GEMM1)

// capacity caps (expected sizes ~13 / ~180 / ~2600 nodes; huge slack)
#define CAP_F2 2048
#define CAP_E3 4096
#define CAP_F1 32768
#define CAP_E2 65536
#define CAP_F0 131072
#define CAP_E1 262144

// counters: cnt[0]=F2, cnt[1]=E3, cnt[2]=F1, cnt[3]=E2, cnt[4]=F0, cnt[5]=E1

__global__ void k_seed(int* __restrict__ mark, int* __restrict__ F2,
                       int* __restrict__ cnt, int last) {
    if (threadIdx.x == 0) {
        mark[last] = M2;
        F2[0] = last;
        cnt[0] = 1;
    }
}

// One backward-BFS level: edges with marked dst are appended to Elist; their
// srcs get setBit + appended to Flist. Also folds in the "self-loop" append:
// threads i < selfCnt propagate selfList[i] into Flist (frontier ⊆ next level).
__global__ void k_mark(const int* __restrict__ src, const int* __restrict__ dst, int E,
                       int* __restrict__ mark, int checkBit, int setBit, int last,
                       int2* __restrict__ Elist, int Ecap, int* __restrict__ eCnt,
                       int* __restrict__ Flist, int Fcap, int* __restrict__ fCnt,
                       const int* __restrict__ selfList, const int* __restrict__ selfCnt,
                       int selfCap)
{
    int i = blockIdx.x * blockDim.x + threadIdx.x;

    if (selfList) {
        int sc = *selfCnt; if (sc > selfCap) sc = selfCap;
        if (i < sc) {
            int v = selfList[i];
            if (!(atomicOr(&mark[v], setBit) & setBit)) {
                int p = atomicAdd(fCnt, 1);
                if (p < Fcap) Flist[p] = v;
            }
        }
    }
    if (i < E) {
        int d = dst[i];
        bool hit = checkBit ? ((mark[d] & checkBit) != 0) : (d == last);
        if (hit) {
            int s = src[i];
            int p = atomicAdd(eCnt, 1);
            if (p < Ecap) Elist[p] = make_int2(s, d);
            if (!(atomicOr(&mark[s], setBit) & setBit)) {
                int q = atomicAdd(fCnt, 1);
                if (q < Fcap) Flist[q] = s;
            }
        }
    }
}

// in-degree, but only for marked nodes (the only ones whose dinv is used)
__global__ void k_degm(const int* __restrict__ dst, const int* __restrict__ mark,
                       int* __restrict__ deg, int E) {
    int i = blockIdx.x * blockDim.x + threadIdx.x;
    if (i < E) {
        int d = dst[i];
        if (mark[d]) atomicAdd(&deg[d], 1);
    }
}

__global__ void k_dinvm(const int* __restrict__ mark, const int* __restrict__ deg,
                        float* __restrict__ dinv, int n) {
    int i = blockIdx.x * blockDim.x + threadIdx.x;
    if (i < n && mark[i]) dinv[i] = rsqrtf(1.0f + (float)deg[i]);
}

// Row-list GEMM: for v in list: xrow = bias ? relu(Xin[v]+bias) : Xin[v];
// H[v] = xrow @ W. If v is in the next frontier (mark&aggBit, or v==last),
// also init AGG[v] = dinv[v]^2 * H[v]  (the self-loop term).
// W (128x128 fp32, 64 KB) staged in LDS; x broadcast via __shfl.
__global__ __launch_bounds__(256) void k_gemm_rows(
    const int* __restrict__ list, const int* __restrict__ cntPtr, int cap,
    const float* __restrict__ Xin, const float* __restrict__ bias,
    const float* __restrict__ W, const float* __restrict__ dinv,
    const int* __restrict__ mark, int aggBit, int last,
    float* __restrict__ H, float* __restrict__ AGG)
{
    __shared__ float wsm[128][128];   // [k][j], 64 KB
    const int t = threadIdx.x;

    {   // stage W (row-major, matches layout)
        const float4* W4 = (const float4*)W;
        float4* S4 = (float4*)&wsm[0][0];
        #pragma unroll
        for (int it = 0; it < 16; ++it) S4[it * 256 + t] = W4[it * 256 + t];
    }
    __syncthreads();

    int cnt = *cntPtr; if (cnt > cap) cnt = cap;
    const int wave = t >> 6, lane = t & 63;

    for (int base = blockIdx.x * 4; base < cnt; base += gridDim.x * 4) {
        int r = base + wave;
        if (r >= cnt) continue;
        int v = list[r];
        size_t off = (size_t)v * NF;

        float x0, x1;
        if (bias) {
            x0 = fmaxf(Xin[off + lane]      + bias[lane],      0.f);
            x1 = fmaxf(Xin[off + lane + 64] + bias[lane + 64], 0.f);
        } else {
            x0 = Xin[off + lane];
            x1 = Xin[off + lane + 64];
        }

        float a0 = 0.f, a1 = 0.f;
        #pragma unroll 16
        for (int k = 0; k < 64; ++k) {
            float xk = __shfl(x0, k);
            a0 += xk * wsm[k][lane];
            a1 += xk * wsm[k][lane + 64];
        }
        #pragma unroll 16
        for (int k = 0; k < 64; ++k) {
            float xk = __shfl(x1, k);
            a0 += xk * wsm[k + 64][lane];
            a1 += xk * wsm[k + 64][lane + 64];
        }

        H[off + lane]      = a0;
        H[off + lane + 64] = a1;

        bool doAgg = (mark ? ((mark[v] & aggBit) != 0) : false) || (v == last);
        if (doAgg) {
            float di = dinv[v], s2 = di * di;
            AGG[off + lane]      = a0 * s2;
            AGG[off + lane + 64] = a1 * s2;
        }
    }
}

// scatter edge list: AGG[d] += dinv[s]*dinv[d] * H[s]   (tiny, L2-resident)
__global__ void k_scat(const int2* __restrict__ list, const int* __restrict__ cntPtr, int cap,
                       const float* __restrict__ dinv, const float* __restrict__ H,
                       float* __restrict__ AGG)
{
    int cnt = *cntPtr; if (cnt > cap) cnt = cap;
    int t = threadIdx.x;   // 128 threads, one feature each
    for (int i = blockIdx.x; i < cnt; i += gridDim.x) {
        int2 e = list[i];
        float w = dinv[e.x] * dinv[e.y];
        atomicAdd(&AGG[(size_t)e.y * NF + t], H[(size_t)e.x * NF + t] * w);
    }
}

// out = relu(AGG3[last] + b3) @ fcW + fcb
__global__ void k_fc(const float* __restrict__ AGG3, const float* __restrict__ b3,
                     const float* __restrict__ fcW, const float* __restrict__ fcb,
                     float* __restrict__ out, int last)
{
    __shared__ float xrow[NF];
    int j = threadIdx.x;   // 0..63
    size_t off = (size_t)last * NF;
    xrow[j]      = fmaxf(AGG3[off + j]      + b3[j],      0.f);
    xrow[j + 64] = fmaxf(AGG3[off + j + 64] + b3[j + 64], 0.f);
    __syncthreads();
    float acc = fcb[j];
    #pragma unroll 16
    for (int k = 0; k < NF; ++k) acc += xrow[k] * fcW[k * OUTF + j];
    out[j] = acc;
}

extern "C" void kernel_launch(void* const* d_in, const int* in_sizes, int n_in,
                              void* d_out, int out_size, void* d_ws, size_t ws_size,
                              hipStream_t stream)
{
    const float* x    = (const float*)d_in[0];
    const int*   ei   = (const int*)d_in[1];
    const float* W1   = (const float*)d_in[2];
    const float* b1   = (const float*)d_in[3];
    const float* W2   = (const float*)d_in[4];
    const float* b2   = (const float*)d_in[5];
    const float* W3   = (const float*)d_in[6];
    const float* b3   = (const float*)d_in[7];
    const float* fcW  = (const float*)d_in[8];
    const float* fcb  = (const float*)d_in[9];
    float* out = (float*)d_out;

    const int n = in_sizes[0] / NF;       // 50000
    const int E = in_sizes[1] / 2;        // 600000
    const int* src = ei;
    const int* dst = ei + E;
    const int last = n - 1;

    char* wp = (char*)d_ws;
    auto alloc = [&](size_t bytes) -> void* {
        void* r = (void*)wp;
        wp += (bytes + 255) & ~(size_t)255;
        return r;
    };
    // zeroed region: deg | mark | cnt  (one memset)
    int*   deg  = (int*)alloc((size_t)n * 4);
    int*   mark = (int*)alloc((size_t)n * 4);
    int*   cnt  = (int*)alloc(64 * 4);
    size_t zbytes = (char*)wp - (char*)deg;

    float* dinv = (float*)alloc((size_t)n * 4);
    int*   F2   = (int*) alloc(CAP_F2 * 4);
    int2*  E3   = (int2*)alloc(CAP_E3 * 8);
    int*   F1   = (int*) alloc(CAP_F1 * 4);
    int2*  E2   = (int2*)alloc(CAP_E2 * 8);
    int*   F0   = (int*) alloc(CAP_F0 * 4);
    int2*  E1   = (int2*)alloc(CAP_E1 * 8);
    float* H    = (float*)alloc((size_t)n * NF * 4);   // reused per layer
    float* aggA = (float*)alloc((size_t)n * NF * 4);   // layer 1, reused layer 3
    float* aggB = (float*)alloc((size_t)n * NF * 4);   // layer 2

    const int B  = 256;
    const int EB = (E + B - 1) / B;
    const int NB = (n + B - 1) / B;

    hipMemsetAsync(deg, 0, zbytes, stream);
    k_seed<<<1, 64, 0, stream>>>(mark, F2, cnt, last);

    // backward BFS, 3 levels
    k_mark<<<EB, B, 0, stream>>>(src, dst, E, mark, 0,  M2, last,
                                 E3, CAP_E3, &cnt[1], F2, CAP_F2, &cnt[0],
                                 nullptr, nullptr, 0);
    k_mark<<<EB, B, 0, stream>>>(src, dst, E, mark, M2, M1, last,
                                 E2, CAP_E2, &cnt[3], F1, CAP_F1, &cnt[2],
                                 F2, &cnt[0], CAP_F2);
    k_mark<<<EB, B, 0, stream>>>(src, dst, E, mark, M1, M0, last,
                                 E1, CAP_E1, &cnt[5], F0, CAP_F0, &cnt[4],
                                 F1, &cnt[2], CAP_F1);

    // degrees + norm for marked nodes only
    k_degm <<<EB, B, 0, stream>>>(dst, mark, deg, E);
    k_dinvm<<<NB, B, 0, stream>>>(mark, deg, dinv, n);

    // layer 1: H1 = x@W1 on F0 rows; agg1 init on F1 rows; scatter E1
    k_gemm_rows<<<384, B, 0, stream>>>(F0, &cnt[4], CAP_F0, x, nullptr, W1,
                                       dinv, mark, M1, -1, H, aggA);
    k_scat<<<2048, 128, 0, stream>>>(E1, &cnt[5], CAP_E1, dinv, H, aggA);

    // layer 2: H2 = relu(agg1+b1)@W2 on F1 rows; agg2 init on F2; scatter E2
    k_gemm_rows<<<384, B, 0, stream>>>(F1, &cnt[2], CAP_F1, aggA, b1, W2,
                                       dinv, mark, M2, -1, H, aggB);
    k_scat<<<2048, 128, 0, stream>>>(E2, &cnt[3], CAP_E2, dinv, H, aggB);

    // layer 3: H3 = relu(agg2+b2)@W3 on F2 rows; agg3 init on {last}; scatter E3
    k_gemm_rows<<<384, B, 0, stream>>>(F2, &cnt[0], CAP_F2, aggB, b2, W3,
                                       dinv, nullptr, 0, last, H, aggA);
    k_scat<<<2048, 128, 0, stream>>>(E3, &cnt[1], CAP_E3, dinv, H, aggA);

    // fc on relu(agg3[last]+b3)
    k_fc<<<1, 64, 0, stream>>>(aggA, b3, fcW, fcb, out, last);
}